// Round 9
// baseline (129.243 us; speedup 1.0000x reference)
//
#include <hip/hip_runtime.h>
#include <hip/hip_bf16.h>

// One-hot: label (H*W int32) -> out (N, H, W) float32.
// Ideal traffic = 64 MiB read + 512 MiB write (~92 us at copy-class 6.5 TB/s).
//
// Journal:
//  R1 (8 plane-streams/thread, read-once):    130 us (8 concurrent 64MiB-apart write windows = 4.6 TB/s)
//  R3 (nontemporal stores):                   250 us (nt bypasses L2 write-combine; never again)
//  R4 (plane per blockIdx.y, 1 write window): 146 us (writes ~6.5 TB/s; 64MiB int32 re-fetch thrashed L3)
//  R5 (wave-per-plane, staggered):            153 us (8 concurrent aliased windows again)
//  R6 (pack u8 + 16px/thread expand):         185 us (per-THREAD-contiguous stores broke per-instr coalescing)
//  R7 (pack u8 + plane-serial, 4px/thread):   118 us (best; k2 ~6.4 TB/s incl reads. Fat left: 96+ MB
//                                               intermediate pack write/re-read + 13us pack kernel)
//  R8 (bitplanes):                            128 us (k1 reads at 128B lane stride (R6 lesson, read side);
//                                               k2 32B broadcast loads = 8x read transactions)
//
// R9: FUSED, register-resident. Block owns 16384 px; each thread packs its
// 64 labels (16 lane-contiguous int4 loads -> 16 u32 VGPRs), then writes
// plane 0..7 sequentially (lane-contiguous float4 stores, 1KiB/wave/instr).
// Homogeneous work keeps blocks phase-locked -> ~one plane-sized write
// window at a time (R4/R7's proven fast pattern), zero intermediate traffic.

typedef unsigned int u32;

#define PITER 16                       // block iterations; 1024 px each
#define CHUNK_PX (PITER * 1024)        // 16384 px per block

__global__ void __launch_bounds__(256) get_one_hot_59442347376951_kernel(
    const int* __restrict__ label, float* __restrict__ out, int total) {
    const int tid = threadIdx.x;
    const long long base = (long long)blockIdx.x * CHUNK_PX;

    u32 pk[PITER];
#pragma unroll
    for (int it = 0; it < PITER; ++it) {
        // lane-contiguous: instruction 'it' covers 1 KiB/wave
        int4 a = *reinterpret_cast<const int4*>(label + base + it * 1024 + tid * 4);
        pk[it] = (u32)(a.x & 255) | ((u32)(a.y & 255) << 8) |
                 ((u32)(a.z & 255) << 16) | ((u32)(a.w & 255) << 24);
    }

    for (u32 n = 0; n < 8; ++n) {
        float* op = out + (long long)n * total + base;
#pragma unroll
        for (int it = 0; it < PITER; ++it) {
            u32 w = pk[it];
            float4 v;
            v.x = (((w      ) & 255u) == n) ? 1.0f : 0.0f;
            v.y = (((w >> 8 ) & 255u) == n) ? 1.0f : 0.0f;
            v.z = (((w >> 16) & 255u) == n) ? 1.0f : 0.0f;
            v.w = (((w >> 24)       ) == n) ? 1.0f : 0.0f;
            *reinterpret_cast<float4*>(op + it * 1024 + tid * 4) = v;
        }
    }
}

// Fallback (R1 structure) if N != 8 or shape doesn't divide.
__global__ void __launch_bounds__(256) get_one_hot_generic_kernel(
    const int* __restrict__ label, float* __restrict__ out,
    int total, int N) {
    long long i = ((long long)blockIdx.x * blockDim.x + threadIdx.x) * 4;
    if (i >= total) return;
    int4 lab = *reinterpret_cast<const int4*>(label + i);
    for (int n = 0; n < N; ++n) {
        float4 v;
        v.x = (lab.x == n) ? 1.0f : 0.0f;
        v.y = (lab.y == n) ? 1.0f : 0.0f;
        v.z = (lab.z == n) ? 1.0f : 0.0f;
        v.w = (lab.w == n) ? 1.0f : 0.0f;
        *reinterpret_cast<float4*>(out + (long long)n * total + i) = v;
    }
}

extern "C" void kernel_launch(void* const* d_in, const int* in_sizes, int n_in,
                              void* d_out, int out_size, void* d_ws, size_t ws_size,
                              hipStream_t stream) {
    const int* label = (const int*)d_in[0];
    float* out = (float*)d_out;

    int total = in_sizes[0];          // H*W = 16,777,216
    int N = out_size / total;         // 8

    if (N == 8 && total % CHUNK_PX == 0) {
        int grid = total / CHUNK_PX;  // 1024 blocks x 256 threads
        get_one_hot_59442347376951_kernel<<<grid, 256, 0, stream>>>(label, out, total);
    } else {
        int grid = (total / 4 + 255) / 256;
        get_one_hot_generic_kernel<<<grid, 256, 0, stream>>>(label, out, total, N);
    }
}

// Round 10
// 120.363 us; speedup vs baseline: 1.0738x; 1.0738x over previous
//
#include <hip/hip_runtime.h>
#include <hip/hip_bf16.h>

// One-hot: label (H*W int32) -> out (N, H, W) float32.
// Ideal traffic: fused 576 MB (~86 us), two-pass 656 MB (~96 us) at copy-class 6.7 TB/s.
//
// Journal:
//  R1 (8 plane-streams/thread, read-once):    130 us (8 concurrent 64MiB-apart write windows = 4.6 TB/s)
//  R3 (nontemporal stores):                   250 us (nt bypasses L2 write-combine; never again)
//  R4 (plane per blockIdx.y, 1 write window): 146 us (writes ~6.5 TB/s; 64MiB int32 re-fetch thrashed L3)
//  R5 (wave-per-plane, staggered):            153 us (8 concurrent aliased windows again)
//  R6 (pack u8 + 16px/thread expand):         185 us (per-THREAD-contiguous stores broke per-instr coalescing)
//  R7 (pack u8 + plane-serial, 4px/thread):   118 us (best: dispatcher-enforced plane-serial writes)
//  R8 (bitplanes):                            128 us (strided k1 reads + 32B/wave broadcast k2 reads)
//  R9 (fused, block-local plane-serial):      129 us (no global phase lock w/o dispatcher/barrier ->
//                                               degenerates to R1's multi-window regime)
//
// R10 = R7 with both residual defects fixed:
//  - k1 reads were per-thread-contiguous (16B useful / 64B span / instr).
//    Now 4 wave-strided int4 loads: every instruction is lane-contiguous.
//  - k2 was 131072 tiny WGs (1 load + 1 store each) ~= 0.5 WG/cycle dispatch
//    pressure. Now 16 px/thread, 4x fewer WGs, same per-instruction patterns.

typedef unsigned int u32;

// k1: block packs 4096 px. it-loop: int4 load at px it*1024+tid*4 (1KiB/wave),
// pack 4 labels -> u32, store at word it*256+tid (256B/wave).
__global__ void __launch_bounds__(256) pack_labels_kernel(
    const int* __restrict__ label, u32* __restrict__ packed) {
    const int tid = threadIdx.x;
    const long long base = (long long)blockIdx.x * 4096;   // px
    u32* pp = packed + (base >> 2);
#pragma unroll
    for (int it = 0; it < 4; ++it) {
        int4 a = *reinterpret_cast<const int4*>(label + base + it * 1024 + tid * 4);
        pp[it * 256 + tid] = (u32)(a.x & 255) | ((u32)(a.y & 255) << 8) |
                             ((u32)(a.z & 255) << 16) | ((u32)(a.w & 255) << 24);
    }
}

// k2: one plane per blockIdx.y (x fastest -> dispatcher-enforced plane-serial
// write windows). Block expands 4096 px: 4 wave-strided dword loads
// (256B/wave) + 4 wave-strided float4 stores (1KiB/wave).
__global__ void __launch_bounds__(256) expand_kernel(
    const u32* __restrict__ packed, float* __restrict__ out, int total) {
    const u32 n = blockIdx.y;
    const int tid = threadIdx.x;
    const long long base = (long long)blockIdx.x * 4096;   // px within plane
    const u32* pp = packed + (base >> 2);
    float* op = out + (long long)n * total + base;
#pragma unroll
    for (int it = 0; it < 4; ++it) {
        u32 w = pp[it * 256 + tid];
        float4 v;
        v.x = (((w      ) & 255u) == n) ? 1.0f : 0.0f;
        v.y = (((w >> 8 ) & 255u) == n) ? 1.0f : 0.0f;
        v.z = (((w >> 16) & 255u) == n) ? 1.0f : 0.0f;
        v.w = (((w >> 24)       ) == n) ? 1.0f : 0.0f;
        *reinterpret_cast<float4*>(op + it * 1024 + tid * 4) = v;
    }
}

// Fallback (R1 structure) if N != 8 or shape doesn't divide.
__global__ void __launch_bounds__(256) get_one_hot_generic_kernel(
    const int* __restrict__ label, float* __restrict__ out,
    int total, int N) {
    long long i = ((long long)blockIdx.x * blockDim.x + threadIdx.x) * 4;
    if (i >= total) return;
    int4 lab = *reinterpret_cast<const int4*>(label + i);
    for (int n = 0; n < N; ++n) {
        float4 v;
        v.x = (lab.x == n) ? 1.0f : 0.0f;
        v.y = (lab.y == n) ? 1.0f : 0.0f;
        v.z = (lab.z == n) ? 1.0f : 0.0f;
        v.w = (lab.w == n) ? 1.0f : 0.0f;
        *reinterpret_cast<float4*>(out + (long long)n * total + i) = v;
    }
}

extern "C" void kernel_launch(void* const* d_in, const int* in_sizes, int n_in,
                              void* d_out, int out_size, void* d_ws, size_t ws_size,
                              hipStream_t stream) {
    const int* label = (const int*)d_in[0];
    float* out = (float*)d_out;

    int total = in_sizes[0];          // H*W = 16,777,216
    int N = out_size / total;         // 8

    bool fast = (N == 8) && (total % 4096 == 0) && (ws_size >= (size_t)total);
    if (fast) {
        int blocks = total / 4096;    // 4096
        pack_labels_kernel<<<blocks, 256, 0, stream>>>(label, (u32*)d_ws);
        dim3 grid(blocks, N);         // 4096 x 8; x fastest -> plane-serial passes
        expand_kernel<<<grid, 256, 0, stream>>>((const u32*)d_ws, out, total);
    } else {
        int grid = (total / 4 + 255) / 256;
        get_one_hot_generic_kernel<<<grid, 256, 0, stream>>>(label, out, total, N);
    }
}

// Round 11
// 112.123 us; speedup vs baseline: 1.1527x; 1.0735x over previous
//
#include <hip/hip_runtime.h>
#include <hip/hip_bf16.h>

// One-hot: label (H*W int32) -> out (N, H, W) float32.
// Ideal two-pass traffic ~620 MB (~98 us at copy-class 6.3-6.6 TB/s).
//
// Journal:
//  R1 (8 plane-streams/thread, read-once):    130 us (8 concurrent 64MiB-apart write windows = 4.6 TB/s)
//  R3 (nontemporal stores):                   250 us (nt bypasses L2 write-combine; never again)
//  R4 (plane per blockIdx.y, int32 reads):    146 us (write pattern good; 64MiB label re-fetch ~400MB)
//  R5 (wave-per-plane, staggered):            153 us (8 concurrent aliased windows again)
//  R6 (pack u8 + 16px/thread expand):         185 us (per-THREAD-contiguous accesses broke coalescing)
//  R7 (pack u8 + plane-serial, 4px/thread):   118 us (champion structure)
//  R8 (bitplanes):                            128 us (strided k1 reads, 32B/wave broadcast k2 reads)
//  R9 (fused, block-local plane-serial):      129 us (no global phase lock -> R1 regime)
//  R10 (R7 + coalesced k1 + 4x fewer k2 WGs): 120 us (those two factors were immaterial)
//
// R11: 4-bit pack (labels are 0..7). Packed array 16->8 MiB: 1 MiB per
// XCD-L2 slice (stable chunk->XCD map since gridX%8==0), trivially
// L3-resident across the 8 plane passes even under write-stream thrash.
// Word layout keeps EVERY memory instruction lane-contiguous:
//   word[base/8 + q*256 + tid] = px(base+q*2048+tid*4 .. +3) in low nibbles,
//                                px(+1024 .. +3)             in high nibbles.

typedef unsigned int u32;

// k1: block packs 4096 px -> 512 words. 2 iterations x (2 int4 loads @1KiB/wave,
// 1 u32 store @256B/wave).
__global__ void __launch_bounds__(256) pack_labels_kernel(
    const int* __restrict__ label, u32* __restrict__ packed) {
    const int tid = threadIdx.x;
    const long long base = (long long)blockIdx.x * 4096;
    u32* wp = packed + (base >> 3);
#pragma unroll
    for (int q = 0; q < 2; ++q) {
        const int* lp = label + base + q * 2048 + tid * 4;
        int4 a = *reinterpret_cast<const int4*>(lp);          // px p..p+3
        int4 b = *reinterpret_cast<const int4*>(lp + 1024);   // px p+1024..p+1027
        u32 w = (u32)(a.x & 7)        | ((u32)(a.y & 7) << 4)  |
                ((u32)(a.z & 7) << 8) | ((u32)(a.w & 7) << 12) |
                ((u32)(b.x & 7) << 16)| ((u32)(b.y & 7) << 20) |
                ((u32)(b.z & 7) << 24)| ((u32)(b.w & 7) << 28);
        wp[q * 256 + tid] = w;
    }
}

// k2: one plane per blockIdx.y (x fastest -> dispatcher-enforced plane-serial
// write windows). Block expands 4096 px: 2 x (1 u32 load @256B/wave,
// 2 float4 stores @1KiB/wave).
__global__ void __launch_bounds__(256) expand_kernel(
    const u32* __restrict__ packed, float* __restrict__ out, int total) {
    const u32 n = blockIdx.y;
    const int tid = threadIdx.x;
    const long long base = (long long)blockIdx.x * 4096;
    const u32* wp = packed + (base >> 3);
    float* op = out + (long long)n * total + base;
#pragma unroll
    for (int q = 0; q < 2; ++q) {
        u32 w = wp[q * 256 + tid];
        float4 v0, v1;
        v0.x = (((w      ) & 15u) == n) ? 1.0f : 0.0f;
        v0.y = (((w >> 4 ) & 15u) == n) ? 1.0f : 0.0f;
        v0.z = (((w >> 8 ) & 15u) == n) ? 1.0f : 0.0f;
        v0.w = (((w >> 12) & 15u) == n) ? 1.0f : 0.0f;
        v1.x = (((w >> 16) & 15u) == n) ? 1.0f : 0.0f;
        v1.y = (((w >> 20) & 15u) == n) ? 1.0f : 0.0f;
        v1.z = (((w >> 24) & 15u) == n) ? 1.0f : 0.0f;
        v1.w = (((w >> 28)       ) == n) ? 1.0f : 0.0f;
        float* o = op + q * 2048 + tid * 4;
        *reinterpret_cast<float4*>(o)        = v0;
        *reinterpret_cast<float4*>(o + 1024) = v1;
    }
}

// Fallback (R1 structure) if N != 8 or shape doesn't divide.
__global__ void __launch_bounds__(256) get_one_hot_generic_kernel(
    const int* __restrict__ label, float* __restrict__ out,
    int total, int N) {
    long long i = ((long long)blockIdx.x * blockDim.x + threadIdx.x) * 4;
    if (i >= total) return;
    int4 lab = *reinterpret_cast<const int4*>(label + i);
    for (int n = 0; n < N; ++n) {
        float4 v;
        v.x = (lab.x == n) ? 1.0f : 0.0f;
        v.y = (lab.y == n) ? 1.0f : 0.0f;
        v.z = (lab.z == n) ? 1.0f : 0.0f;
        v.w = (lab.w == n) ? 1.0f : 0.0f;
        *reinterpret_cast<float4*>(out + (long long)n * total + i) = v;
    }
}

extern "C" void kernel_launch(void* const* d_in, const int* in_sizes, int n_in,
                              void* d_out, int out_size, void* d_ws, size_t ws_size,
                              hipStream_t stream) {
    const int* label = (const int*)d_in[0];
    float* out = (float*)d_out;

    int total = in_sizes[0];          // H*W = 16,777,216
    int N = out_size / total;         // 8

    bool fast = (N == 8) && (total % 4096 == 0) && (ws_size >= (size_t)(total / 2));
    if (fast) {
        int blocks = total / 4096;    // 4096
        pack_labels_kernel<<<blocks, 256, 0, stream>>>(label, (u32*)d_ws);
        dim3 grid(blocks, N);         // 4096 x 8; x fastest -> plane-serial passes
        expand_kernel<<<grid, 256, 0, stream>>>((const u32*)d_ws, out, total);
    } else {
        int grid = (total / 4 + 255) / 256;
        get_one_hot_generic_kernel<<<grid, 256, 0, stream>>>(label, out, total, N);
    }
}